// Round 8
// baseline (938.205 us; speedup 1.0000x reference)
//
#include <hip/hip_runtime.h>

typedef unsigned short ushort_t;

constexpr int NN = 100000;   // nodes
constexpr int EE = 1600000;  // edges
constexpr int PP = 100000;   // pos/neg samples
constexpr int DH = 128;
constexpr int DM = 512;

// multisplit CSR-build params
constexpr int BSH = 8;                         // bucket = dst >> 8
constexpr int BUCKET = 256;                    // nodes per bucket
constexpr int NB = (NN + BUCKET - 1) / BUCKET; // 391 buckets
constexpr int CHUNK = 4096;                    // edges per chunk
constexpr int NC = (EE + CHUNK - 1) / CHUNK;   // 391 chunks
constexpr int CAP = 6144;                      // passC LDS edge-stage capacity

using frag_b16 = __attribute__((ext_vector_type(8))) short;   // 8 bf16 (4 VGPRs)
using frag_f32 = __attribute__((ext_vector_type(4))) float;   // 4 fp32 acc

union FragU {
  ushort_t s[8];
  uint4 u;
  frag_b16 f;
};

// split fp32 into bf16 hi (truncate) + bf16 lo (RNE of residual): x ~= hi+lo, err ~2^-17|x|
__device__ inline void split_bf16(float x, ushort_t& hi, ushort_t& lo) {
  unsigned int bx = __float_as_uint(x);
  hi = (ushort_t)(bx >> 16);
  float hf = __uint_as_float(bx & 0xFFFF0000u);
  float r = x - hf;
  unsigned int br = __float_as_uint(r);
  unsigned int rb = br + 0x7FFFu + ((br >> 16) & 1u);  // RNE
  lo = (ushort_t)(rb >> 16);
}

__device__ inline ushort_t rne_bf16(float x) {
  unsigned int u = __float_as_uint(x);
  unsigned int r = u + 0x7FFFu + ((u >> 16) & 1u);
  return (ushort_t)(r >> 16);
}

// unpack 2 bf16 from packed uint: low half -> a (even col), high half -> b (odd col)
__device__ inline void bf2x(unsigned int u, float& a, float& b) {
  a = __uint_as_float(u << 16);
  b = __uint_as_float(u & 0xFFFF0000u);
}

// load one 16B weight record (8 bf16, MFMA B-frag order)
__device__ inline void ldrec(const ushort_t* __restrict__ wp, int tile, int lane, FragU& f) {
  f.u = *(const uint4*)(wp + ((size_t)(tile * 64 + lane)) * 8);
}

// ---------------- CSR build: degree + node-level scan (unchanged core) ----------------

__global__ void hist_kernel(const int* __restrict__ dst, int* __restrict__ deg) {
  int i = blockIdx.x * 256 + threadIdx.x;
  if (i < EE) atomicAdd(&deg[dst[i]], 1);
}

__global__ void scan1_kernel(const int* __restrict__ deg, int* __restrict__ inc,
                             int* __restrict__ bsum) {
  __shared__ int buf[2][512];
  int base = blockIdx.x * 512;
  for (int i = threadIdx.x; i < 512; i += 256) {
    int g = base + i;
    buf[0][i] = (g < NN) ? deg[g] : 0;
  }
  __syncthreads();
  int cur = 0;
  for (int off = 1; off < 512; off <<= 1) {
    int nxt = cur ^ 1;
    for (int i = threadIdx.x; i < 512; i += 256) {
      int v = buf[cur][i];
      if (i >= off) v += buf[cur][i - off];
      buf[nxt][i] = v;
    }
    __syncthreads();
    cur = nxt;
  }
  for (int i = threadIdx.x; i < 512; i += 256) {
    int g = base + i;
    if (g < NN) inc[g] = buf[cur][i];
  }
  if (threadIdx.x == 0) bsum[blockIdx.x] = buf[cur][511];
}

__global__ void scan2_kernel(int* __restrict__ bsum, int nb) {
  __shared__ int buf[2][256];
  int i = threadIdx.x;
  buf[0][i] = (i < nb) ? bsum[i] : 0;
  __syncthreads();
  int cur = 0;
  for (int off = 1; off < 256; off <<= 1) {
    int nxt = cur ^ 1;
    int v = buf[cur][i];
    if (i >= off) v += buf[cur][i - off];
    buf[nxt][i] = v;
    __syncthreads();
    cur = nxt;
  }
  if (i < nb) bsum[i] = (i == 0) ? 0 : buf[cur][i - 1];
}

__global__ void scan3_kernel(const int* __restrict__ inc, const int* __restrict__ deg,
                             const int* __restrict__ bsum, int* __restrict__ row_off) {
  int i = blockIdx.x * 256 + threadIdx.x;
  if (i < NN) {
    int excl = inc[i] - deg[i] + bsum[i >> 9];
    row_off[i] = excl;
    if (i == NN - 1) row_off[NN] = excl + deg[i];  // == EE
  }
}

// ---------------- multisplit passes (replace atomic scatter; write-amp ~1x) ------------

// passA: per-(chunk c, bucket b) edge counts via LDS histogram -> cnt[b*NC + c]
__global__ __launch_bounds__(256) void passA_kernel(const int* __restrict__ edst,
                                                    int* __restrict__ cnt) {
  __shared__ int lcnt[NB];
  const int c = blockIdx.x, tid = threadIdx.x;
  for (int b = tid; b < NB; b += 256) lcnt[b] = 0;
  __syncthreads();
  int base = c * CHUNK;
  #pragma unroll
  for (int j = 0; j < CHUNK / 256; ++j) {
    int i = base + tid + j * 256;
    if (i < EE) atomicAdd(&lcnt[edst[i] >> BSH], 1);
  }
  __syncthreads();
  for (int b = tid; b < NB; b += 256) cnt[(size_t)b * NC + c] = lcnt[b];
}

// offs: cnt[b][c] -> exclusive offset = row_off[b*BUCKET] + sum_{c'<c} cnt[b][c']
__global__ __launch_bounds__(512) void offs_kernel(const int* __restrict__ row_off,
                                                   int* __restrict__ cnt) {
  int b = threadIdx.x;
  if (b >= NB) return;
  int acc = row_off[b * BUCKET];
  for (int g = 0; g < (NC + 31) / 32; ++g) {
    int buf[32];
    #pragma unroll
    for (int j = 0; j < 32; ++j) {
      int c = g * 32 + j;
      buf[j] = (c < NC) ? cnt[(size_t)b * NC + c] : 0;
    }
    #pragma unroll
    for (int j = 0; j < 32; ++j) {
      int c = g * 32 + j;
      if (c < NC) {
        int t = buf[j];
        cnt[(size_t)b * NC + c] = acc;
        acc += t;
      }
    }
  }
}

// passB: rank edges within (chunk,bucket) via LDS cursors; write packed
// (dst_local<<17 | src) into chunk-exclusive ranges of ebuf (full-line writes).
__global__ __launch_bounds__(256) void passB_kernel(const int* __restrict__ esrc,
                                                    const int* __restrict__ edst,
                                                    const int* __restrict__ cnt,
                                                    unsigned int* __restrict__ ebuf) {
  __shared__ int lcur[NB];
  const int c = blockIdx.x, tid = threadIdx.x;
  for (int b = tid; b < NB; b += 256) lcur[b] = cnt[(size_t)b * NC + c];
  __syncthreads();
  int base = c * CHUNK;
  #pragma unroll
  for (int j = 0; j < CHUNK / 256; ++j) {
    int i = base + tid + j * 256;
    if (i < EE) {
      int d = edst[i];
      int b = d >> BSH;
      int pos = atomicAdd(&lcur[b], 1);
      ebuf[pos] = ((unsigned int)(d & (BUCKET - 1)) << 17) | (unsigned int)esrc[i];
    }
  }
}

// passC: per-bucket local counting sort; scatter src into the bucket's
// WG-exclusive csr range (node-exact order; write-amp ~1x).
__global__ __launch_bounds__(256) void passC_kernel(const int* __restrict__ row_off,
                                                    const unsigned int* __restrict__ ebuf,
                                                    int* __restrict__ csr) {
  __shared__ int hist[BUCKET];
  __shared__ int sc[2][BUCKET];
  __shared__ unsigned int stage[CAP];
  const int b = blockIdx.x, tid = threadIdx.x;
  int base = row_off[b * BUCKET];
  int node_end = (b + 1) * BUCKET;
  if (node_end > NN) node_end = NN;
  int end = row_off[node_end];
  int len = end - base;
  hist[tid] = 0;
  __syncthreads();
  for (int i = tid; i < len; i += 256) {
    unsigned int v = ebuf[base + i];
    if (i < CAP) stage[i] = v;
    atomicAdd(&hist[v >> 17], 1);
  }
  __syncthreads();
  // exclusive scan of hist (256 entries, 256 threads)
  sc[0][tid] = hist[tid];
  __syncthreads();
  int cur = 0;
  for (int off = 1; off < BUCKET; off <<= 1) {
    int nxt = cur ^ 1;
    int v = sc[cur][tid];
    if (tid >= off) v += sc[cur][tid - off];
    sc[nxt][tid] = v;
    __syncthreads();
    cur = nxt;
  }
  int excl = (tid == 0) ? 0 : sc[cur][tid - 1];
  __syncthreads();
  hist[tid] = excl;  // hist becomes per-node cursor (base-relative)
  __syncthreads();
  for (int i = tid; i < len; i += 256) {
    unsigned int v = (i < CAP) ? stage[i] : ebuf[base + i];
    int d = (int)(v >> 17);
    int s = (int)(v & 0x1FFFFu);
    int pos = base + atomicAdd(&hist[d], 1);
    csr[pos] = s;
  }
}

// ---------------- weight packing: MFMA B-frag order, 16B records, RNE bf16 ----------
// record r = tile_global*64+lane holds 8 bf16 at wp + r*8 (ushorts).
// W1 [L][128(K)][512(N)]: tile = tn*4+tk (tn<32,tk<4), n=tn*16+(lane&15), k=tk*32+(lane>>4)*8+j
__global__ void pack_w1_kernel(const float* __restrict__ W1, ushort_t* __restrict__ wp) {
  int t = blockIdx.x * 256 + threadIdx.x;
  if (t >= 3 * 128 * 64) return;
  int lane = t & 63;
  int tile = t >> 6;
  int tk = tile & 3;
  int tn = (tile >> 2) & 31;
  int layer = tile >> 7;
  int n = tn * 16 + (lane & 15);
  int k0 = tk * 32 + (lane >> 4) * 8;
  const float* src = W1 + (size_t)layer * DH * DM;
  size_t dst = (size_t)t * 8;
  #pragma unroll
  for (int j = 0; j < 8; ++j) wp[dst + j] = rne_bf16(src[(size_t)(k0 + j) * DM + n]);
}

// W2 [L][512(K)][128(N)]: tile = tn*16+tk (tn<8, tk<16)
__global__ void pack_w2_kernel(const float* __restrict__ W2, ushort_t* __restrict__ wp) {
  int t = blockIdx.x * 256 + threadIdx.x;
  if (t >= 3 * 128 * 64) return;
  int lane = t & 63;
  int tile = t >> 6;
  int tk = tile & 15;
  int tn = (tile >> 4) & 7;
  int layer = tile >> 7;
  int n = tn * 16 + (lane & 15);
  int k0 = tk * 32 + (lane >> 4) * 8;
  const float* src = W2 + (size_t)layer * DM * DH;
  size_t dst = (size_t)t * 8;
  #pragma unroll
  for (int j = 0; j < 8; ++j) wp[dst + j] = rne_bf16(src[(size_t)(k0 + j) * DH + n]);
}

// ---------------- x -> bf16 convert (layer-0 gather source) ----------------
__global__ void cvt_bf16_kernel(const float* __restrict__ x, ushort_t* __restrict__ xb) {
  int i = blockIdx.x * 256 + threadIdx.x;  // n = NN*DH/4 quads
  if (i < NN * DH / 4) {
    float4 v = ((const float4*)x)[i];
    ushort4 o;
    o.x = rne_bf16(v.x); o.y = rne_bf16(v.y); o.z = rne_bf16(v.z); o.w = rne_bf16(v.w);
    ((ushort4*)xb)[i] = o;
  }
}

// ---------------- aggregation: s[dst] = h[dst] + sum h[src] over bf16 h ----------------
// 16 lanes/row, 16 B (8 bf16 cols) per lane; 4 gathers in flight.
__global__ __launch_bounds__(256) void agg_kernel(const ushort_t* __restrict__ hbf,
                                                  const int* __restrict__ row_off,
                                                  const int* __restrict__ csr,
                                                  ushort_t* __restrict__ s_hi,
                                                  ushort_t* __restrict__ s_lo) {
  int t = blockIdx.x * 256 + threadIdx.x;
  int grp = t >> 4;
  int lane = t & 15;
  if (grp >= NN) return;
  const uint4* hp = (const uint4*)hbf;  // 16 uint4 per 128-col row
  float acc[8];
  {
    uint4 v = hp[(size_t)grp * 16 + lane];
    bf2x(v.x, acc[0], acc[1]);
    bf2x(v.y, acc[2], acc[3]);
    bf2x(v.z, acc[4], acc[5]);
    bf2x(v.w, acc[6], acc[7]);
  }
  int e = row_off[grp];
  int e1 = row_off[grp + 1];
  float f0, f1;
  for (; e + 3 < e1; e += 4) {  // four gathers in flight
    uint4 a = hp[(size_t)csr[e] * 16 + lane];
    uint4 b = hp[(size_t)csr[e + 1] * 16 + lane];
    uint4 c = hp[(size_t)csr[e + 2] * 16 + lane];
    uint4 d = hp[(size_t)csr[e + 3] * 16 + lane];
    bf2x(a.x, f0, f1); acc[0] += f0; acc[1] += f1;
    bf2x(a.y, f0, f1); acc[2] += f0; acc[3] += f1;
    bf2x(a.z, f0, f1); acc[4] += f0; acc[5] += f1;
    bf2x(a.w, f0, f1); acc[6] += f0; acc[7] += f1;
    bf2x(b.x, f0, f1); acc[0] += f0; acc[1] += f1;
    bf2x(b.y, f0, f1); acc[2] += f0; acc[3] += f1;
    bf2x(b.z, f0, f1); acc[4] += f0; acc[5] += f1;
    bf2x(b.w, f0, f1); acc[6] += f0; acc[7] += f1;
    bf2x(c.x, f0, f1); acc[0] += f0; acc[1] += f1;
    bf2x(c.y, f0, f1); acc[2] += f0; acc[3] += f1;
    bf2x(c.z, f0, f1); acc[4] += f0; acc[5] += f1;
    bf2x(c.w, f0, f1); acc[6] += f0; acc[7] += f1;
    bf2x(d.x, f0, f1); acc[0] += f0; acc[1] += f1;
    bf2x(d.y, f0, f1); acc[2] += f0; acc[3] += f1;
    bf2x(d.z, f0, f1); acc[4] += f0; acc[5] += f1;
    bf2x(d.w, f0, f1); acc[6] += f0; acc[7] += f1;
  }
  for (; e < e1; ++e) {
    uint4 a = hp[(size_t)csr[e] * 16 + lane];
    bf2x(a.x, f0, f1); acc[0] += f0; acc[1] += f1;
    bf2x(a.y, f0, f1); acc[2] += f0; acc[3] += f1;
    bf2x(a.z, f0, f1); acc[4] += f0; acc[5] += f1;
    bf2x(a.w, f0, f1); acc[6] += f0; acc[7] += f1;
  }
  // split to hi/lo planes, 16 B per lane each
  unsigned int hw[4], lw[4];
  #pragma unroll
  for (int i = 0; i < 4; ++i) {
    ushort_t h0, l0, h1, l1;
    split_bf16(acc[2 * i], h0, l0);
    split_bf16(acc[2 * i + 1], h1, l1);
    hw[i] = (unsigned int)h0 | ((unsigned int)h1 << 16);
    lw[i] = (unsigned int)l0 | ((unsigned int)l1 << 16);
  }
  size_t o = (size_t)grp * DH + lane * 8;
  *(uint4*)(s_hi + o) = make_uint4(hw[0], hw[1], hw[2], hw[3]);
  *(uint4*)(s_lo + o) = make_uint4(lw[0], lw[1], lw[2], lw[3]);
}

// ---------------- fused MFMA MLP, 32 rows/wave (2 m-tiles), 2-pass split ----------
// Block = 128 threads (2 waves), 64 rows. Wave w owns rows 32w..32w+31.
// Passes: a_hi*b + a_lo*b (weights single RNE bf16). z through wave-private LDS
// slice -> no __syncthreads. Weight records batched 4-8 in flight for ILP.
__global__ __launch_bounds__(128) void mlp_kernel(
    const ushort_t* __restrict__ s_hi, const ushort_t* __restrict__ s_lo,
    const ushort_t* __restrict__ w1p, const float* __restrict__ b1s,
    const ushort_t* __restrict__ w2p, const float* __restrict__ b2s,
    float* __restrict__ hout_f32, ushort_t* __restrict__ hout_bf16) {
  __shared__ float zt[64 * 66];  // [k_z 0..63][m 0..63 +pad2]
  const int tid = threadIdx.x;
  const int wave = tid >> 6;      // 0..1
  const int lane = tid & 63;
  const int quad = lane >> 4;
  const int l15 = lane & 15;
  const int m_base = wave * 32;
  const int row0 = blockIdx.x * 64;

  // ---- A-fragments: 2 m-tiles x 4 k-tiles, bf16 hi/lo, in registers all kernel ----
  frag_b16 a_hi[2][4], a_lo[2][4];
  #pragma unroll
  for (int ms = 0; ms < 2; ++ms) {
    int gr = row0 + m_base + ms * 16 + l15;
    if (gr >= NN) gr = NN - 1;  // clamp: stores are guarded
    #pragma unroll
    for (int tk = 0; tk < 4; ++tk) {
      size_t o = (size_t)gr * DH + tk * 32 + quad * 8;
      FragU uh, ul;
      uh.u = *(const uint4*)(s_hi + o);
      ul.u = *(const uint4*)(s_lo + o);
      a_hi[ms][tk] = uh.f;
      a_lo[ms][tk] = ul.f;
    }
  }

  frag_f32 hacc[2][8];
  #pragma unroll
  for (int ms = 0; ms < 2; ++ms)
    #pragma unroll
    for (int tn = 0; tn < 8; ++tn) hacc[ms][tn] = {0.f, 0.f, 0.f, 0.f};

  for (int ch = 0; ch < 8; ++ch) {
    // ---- stage A: z[64 rows][64-col chunk] = relu(s @ W1[:, ch*64..+64] + b1) ----
    frag_f32 za[2][4];
    #pragma unroll
    for (int ms = 0; ms < 2; ++ms)
      #pragma unroll
      for (int tn = 0; tn < 4; ++tn) za[ms][tn] = {0.f, 0.f, 0.f, 0.f};

    FragU wb[2][4];
    #pragma unroll
    for (int tn = 0; tn < 4; ++tn) ldrec(w1p, ch * 16 + tn * 4, lane, wb[0][tn]);
    #pragma unroll
    for (int tk = 0; tk < 4; ++tk) {
      int cur = tk & 1, nxt = cur ^ 1;
      if (tk < 3) {
        #pragma unroll
        for (int tn = 0; tn < 4; ++tn)
          ldrec(w1p, ch * 16 + tn * 4 + tk + 1, lane, wb[nxt][tn]);
      }
      #pragma unroll
      for (int tn = 0; tn < 4; ++tn) {
        #pragma unroll
        for (int ms = 0; ms < 2; ++ms) {
          za[ms][tn] = __builtin_amdgcn_mfma_f32_16x16x32_bf16(a_hi[ms][tk], wb[cur][tn].f,
                                                               za[ms][tn], 0, 0, 0);
          za[ms][tn] = __builtin_amdgcn_mfma_f32_16x16x32_bf16(a_lo[ms][tk], wb[cur][tn].f,
                                                               za[ms][tn], 0, 0, 0);
        }
      }
    }

    // relu+bias, write wave-private zt slice (all 64 k-cols, this wave's 32 m)
    #pragma unroll
    for (int tn = 0; tn < 4; ++tn) {
      float b1v = b1s[ch * 64 + tn * 16 + l15];
      #pragma unroll
      for (int ms = 0; ms < 2; ++ms) {
        float z0 = fmaxf(za[ms][tn][0] + b1v, 0.f);
        float z1 = fmaxf(za[ms][tn][1] + b1v, 0.f);
        float z2 = fmaxf(za[ms][tn][2] + b1v, 0.f);
        float z3 = fmaxf(za[ms][tn][3] + b1v, 0.f);
        float* zp = &zt[(tn * 16 + l15) * 66 + m_base + ms * 16 + quad * 4];
        *(float2*)zp = make_float2(z0, z1);
        *(float2*)(zp + 2) = make_float2(z2, z3);
      }
    }
    // no barrier: each wave reads back only its own m-slice (lgkmcnt ordering)

    // ---- stage B: hacc += z @ W2[ch*64..+64, :] ----
    #pragma unroll
    for (int kt = 0; kt < 2; ++kt) {
      int ktg = ch * 2 + kt;
      FragU wb2[8];
      #pragma unroll
      for (int tn = 0; tn < 8; ++tn) ldrec(w2p, tn * 16 + ktg, lane, wb2[tn]);
      FragU zh[2], zl[2];
      #pragma unroll
      for (int ms = 0; ms < 2; ++ms) {
        #pragma unroll
        for (int j = 0; j < 8; ++j) {
          int k = kt * 32 + quad * 8 + j;
          float v = zt[k * 66 + m_base + ms * 16 + l15];
          split_bf16(v, zh[ms].s[j], zl[ms].s[j]);
        }
      }
      #pragma unroll
      for (int tn = 0; tn < 8; ++tn) {
        #pragma unroll
        for (int ms = 0; ms < 2; ++ms) {
          hacc[ms][tn] = __builtin_amdgcn_mfma_f32_16x16x32_bf16(zh[ms].f, wb2[tn].f,
                                                                 hacc[ms][tn], 0, 0, 0);
          hacc[ms][tn] = __builtin_amdgcn_mfma_f32_16x16x32_bf16(zl[ms].f, wb2[tn].f,
                                                                 hacc[ms][tn], 0, 0, 0);
        }
      }
    }
  }

  // ---- epilogue: h = relu(hacc + b2) -> fp32 and/or bf16 ----
  #pragma unroll
  for (int tn = 0; tn < 8; ++tn) {
    int col = tn * 16 + l15;
    float b2v = b2s[col];
    #pragma unroll
    for (int ms = 0; ms < 2; ++ms) {
      #pragma unroll
      for (int r = 0; r < 4; ++r) {
        int gr = row0 + m_base + ms * 16 + quad * 4 + r;
        if (gr < NN) {
          float v = fmaxf(hacc[ms][tn][r] + b2v, 0.f);
          if (hout_f32) hout_f32[(size_t)gr * DH + col] = v;
          if (hout_bf16) hout_bf16[(size_t)gr * DH + col] = rne_bf16(v);
        }
      }
    }
  }
}

// ---------------- link predictor (fp32 VALU, reads final fp32 h) ----------------
__global__ __launch_bounds__(256) void predict_kernel(
    const float* __restrict__ h, const int* __restrict__ psrc, const int* __restrict__ pdst,
    const int* __restrict__ nsrc, const int* __restrict__ ndst,
    const float* __restrict__ Wp1, const float* __restrict__ bp1,
    const float* __restrict__ Wp2, const float* __restrict__ bp2,
    float* __restrict__ out) {
  __shared__ float g_tile[64 * 132];
  const int tid = threadIdx.x;
  const int s0 = blockIdx.x * 64;

  #pragma unroll
  for (int i = 0; i < 8; ++i) {
    int idx = tid + i * 256;
    int smp = s0 + (idx >> 5);
    int c4 = (idx & 31) << 2;
    float4 g = make_float4(0.f, 0.f, 0.f, 0.f);
    if (smp < 2 * PP) {
      int si = (smp < PP) ? psrc[smp] : nsrc[smp - PP];
      int di = (smp < PP) ? pdst[smp] : ndst[smp - PP];
      float4 a = *(const float4*)(h + (size_t)si * DH + c4);
      float4 b = *(const float4*)(h + (size_t)di * DH + c4);
      g = make_float4(a.x * b.x, a.y * b.y, a.z * b.z, a.w * b.w);
    }
    *(float4*)(&g_tile[(idx >> 5) * 132 + c4]) = g;
  }
  __syncthreads();

  const int tr = (tid >> 4) << 2;
  const int tc = (tid & 15) << 2;
  float z[4][4];
  #pragma unroll
  for (int r = 0; r < 4; ++r)
    #pragma unroll
    for (int c = 0; c < 4; ++c) z[r][c] = 0.f;

  for (int k = 0; k < DH; ++k) {
    float4 w = *(const float4*)(Wp1 + ((size_t)k << 6) + tc);
    float a[4];
    #pragma unroll
    for (int r = 0; r < 4; ++r) a[r] = g_tile[(tr + r) * 132 + k];
    #pragma unroll
    for (int r = 0; r < 4; ++r) {
      z[r][0] = fmaf(a[r], w.x, z[r][0]);
      z[r][1] = fmaf(a[r], w.y, z[r][1]);
      z[r][2] = fmaf(a[r], w.z, z[r][2]);
      z[r][3] = fmaf(a[r], w.w, z[r][3]);
    }
  }

  float4 b1v = *(const float4*)(bp1 + tc);
  float4 w2v = *(const float4*)(Wp2 + tc);
  float part[4];
  #pragma unroll
  for (int r = 0; r < 4; ++r) {
    part[r] = fmaxf(z[r][0] + b1v.x, 0.f) * w2v.x +
              fmaxf(z[r][1] + b1v.y, 0.f) * w2v.y +
              fmaxf(z[r][2] + b1v.z, 0.f) * w2v.z +
              fmaxf(z[r][3] + b1v.w, 0.f) * w2v.w;
  }
  #pragma unroll
  for (int off = 1; off < 16; off <<= 1) {
    #pragma unroll
    for (int r = 0; r < 4; ++r) part[r] += __shfl_xor(part[r], off, 64);
  }
  if ((tid & 15) == 0) {
    float bias = bp2[0];
    #pragma unroll
    for (int r = 0; r < 4; ++r) {
      int smp = s0 + tr + r;
      if (smp < 2 * PP) out[smp] = part[r] + bias;
    }
  }
}

// ---------------- launcher ----------------
extern "C" void kernel_launch(void* const* d_in, const int* in_sizes, int n_in,
                              void* d_out, int out_size, void* d_ws, size_t ws_size,
                              hipStream_t stream) {
  const float* x   = (const float*)d_in[0];
  const float* W1  = (const float*)d_in[1];
  const float* b1  = (const float*)d_in[2];
  const float* W2  = (const float*)d_in[3];
  const float* b2  = (const float*)d_in[4];
  const float* Wp1 = (const float*)d_in[5];
  const float* bp1 = (const float*)d_in[6];
  const float* Wp2 = (const float*)d_in[7];
  const float* bp2 = (const float*)d_in[8];
  const int* esrc = (const int*)d_in[9];
  const int* edst = (const int*)d_in[10];
  const int* psrc = (const int*)d_in[11];
  const int* pdst = (const int*)d_in[12];
  const int* nsrc = (const int*)d_in[13];
  const int* ndst = (const int*)d_in[14];

  float* out = (float*)d_out;
  float* out_pred = out;               // [2P]
  float* hbuf = out + 2 * (size_t)PP;  // [N,128] fp32 final h
  // intermediate bf16 h lives in the (dead until layer-2) hbuf region
  ushort_t* hbf = (ushort_t*)hbuf;     // [N,128] bf16 (25.6 MB of the 51.2 MB region)

  // ---- workspace layout (~58.7 MB persistent) ----
  char* w = (char*)d_ws;
  ushort_t* s_hi = (ushort_t*)w;                        // N*128 bf16 = 25.6 MB
  ushort_t* s_lo = s_hi + (size_t)NN * DH;              // 25.6 MB
  ushort_t* w1p  = s_lo + (size_t)NN * DH;              // 3*128*64*8 ushorts = 393 KB
  ushort_t* w2p  = w1p + 3 * 128 * 64 * 8;              // 393 KB
  int* row_off = (int*)(w2p + 3 * 128 * 64 * 8);        // N+1
  int* csr     = row_off + (NN + 1);                    // E (6.4 MB)
  // CSR-build scratch aliases the (not-yet-written) s_hi region (~7.8 MB < 25.6 MB):
  int* deg  = (int*)w;
  int* inc  = deg + NN;
  int* bsum = inc + NN;
  int* cnt  = bsum + 256;                               // NB*NC ints = 612 KB
  unsigned int* ebuf = (unsigned int*)(cnt + NB * NC);  // E packed = 6.4 MB

  // ---- CSR build: degree + node scan, then 3-phase multisplit ----
  hipMemsetAsync(deg, 0, NN * sizeof(int), stream);
  hist_kernel<<<(EE + 255) / 256, 256, 0, stream>>>(edst, deg);
  scan1_kernel<<<(NN + 511) / 512, 256, 0, stream>>>(deg, inc, bsum);
  scan2_kernel<<<1, 256, 0, stream>>>(bsum, (NN + 511) / 512);
  scan3_kernel<<<(NN + 255) / 256, 256, 0, stream>>>(inc, deg, bsum, row_off);
  passA_kernel<<<NC, 256, 0, stream>>>(edst, cnt);
  offs_kernel<<<1, 512, 0, stream>>>(row_off, cnt);
  passB_kernel<<<NC, 256, 0, stream>>>(esrc, edst, cnt, ebuf);
  passC_kernel<<<NB, 256, 0, stream>>>(row_off, ebuf, csr);

  // ---- pack weights (RNE bf16, MFMA fragment order, 16B records) ----
  pack_w1_kernel<<<96, 256, 0, stream>>>(W1, w1p);
  pack_w2_kernel<<<96, 256, 0, stream>>>(W2, w2p);

  // ---- x -> bf16 for layer-0 gather ----
  cvt_bf16_kernel<<<(NN * DH / 4 + 255) / 256, 256, 0, stream>>>(x, hbf);

  // ---- 3 GIN layers: agg(hbf -> s planes), mlp(s -> hbf or hbuf) ----
  for (int l = 0; l < 3; ++l) {
    agg_kernel<<<(NN * 16 + 255) / 256, 256, 0, stream>>>(hbf, row_off, csr, s_hi, s_lo);
    mlp_kernel<<<(NN + 63) / 64, 128, 0, stream>>>(
        s_hi, s_lo,
        w1p + (size_t)l * 128 * 64 * 8, b1 + (size_t)l * DM,
        w2p + (size_t)l * 128 * 64 * 8, b2 + (size_t)l * DH,
        (l == 2) ? hbuf : nullptr, (l == 2) ? nullptr : hbf);
  }

  // ---- link prediction ----
  predict_kernel<<<(2 * PP + 63) / 64, 256, 0, stream>>>(
      hbuf, psrc, pdst, nsrc, ndst, Wp1, bp1, Wp2, bp2, out_pred);
}